// Round 3
// baseline (342.329 us; speedup 1.0000x reference)
//
#include <hip/hip_runtime.h>
#include <hip/hip_bf16.h>

#define DEVINL __device__ __forceinline__

typedef float f32x4 __attribute__((ext_vector_type(4)));
typedef __bf16 bf16x8 __attribute__((ext_vector_type(8)));

DEVINL void gld_lds16(const void* g, void* l) {
  __builtin_amdgcn_global_load_lds(
      (const __attribute__((address_space(1))) unsigned int*)g,
      (__attribute__((address_space(3))) unsigned int*)l, 16, 0, 0);
}

DEVINL unsigned short f2bf(float f) {
  __bf16 h = (__bf16)f;
  return __builtin_bit_cast(unsigned short, h);
}

DEVINL f32x4 mfma16(bf16x8 a, bf16x8 b, f32x4 c) {
  return __builtin_amdgcn_mfma_f32_16x16x32_bf16(a, b, c, 0, 0, 0);
}

// ---------------------------------------------------------------------------
// fp32 -> bf16 convert (4 elems/thread), fixed 4M elements (grid 4096 x 256)
// ---------------------------------------------------------------------------
__global__ __launch_bounds__(256) void cvt_kernel(const float* __restrict__ in,
                                                  unsigned short* __restrict__ outp) {
  int i = blockIdx.x * 256 + threadIdx.x;
  float4 v = ((const float4*)in)[i];
  ushort4 o;
  o.x = f2bf(v.x); o.y = f2bf(v.y); o.z = f2bf(v.z); o.w = f2bf(v.w);
  ((ushort4*)outp)[i] = o;
}

// ---------------------------------------------------------------------------
// W[K][N] fp32 -> Wt[N][K] bf16 (32x32 tiles)
// ---------------------------------------------------------------------------
__global__ __launch_bounds__(256) void transpose_cvt(const float* __restrict__ W,
                                                     unsigned short* __restrict__ Wt,
                                                     int K, int N) {
  __shared__ float t[32][33];
  int n0 = blockIdx.x * 32, k0 = blockIdx.y * 32;
  int tx = threadIdx.x & 31, ty = threadIdx.x >> 5;  // ty 0..7
#pragma unroll
  for (int i = 0; i < 4; i++)
    t[ty + i * 8][tx] = W[(size_t)(k0 + ty + i * 8) * N + n0 + tx];
  __syncthreads();
#pragma unroll
  for (int i = 0; i < 4; i++) {
    int n = ty + i * 8;
    Wt[(size_t)(n0 + n) * K + k0 + tx] = f2bf(t[tx][n]);
  }
}

// ---------------------------------------------------------------------------
// GEMM: C[M][N] = A[M][K] @ Bt[N][K]^T + bias ; A,Bt bf16 ; C bf16 or fp32
// 128x128 tile, BK=32, 4 waves, m97-style global_load_lds staging
// ---------------------------------------------------------------------------
template <bool OUT_BF16>
__global__ __launch_bounds__(256) void gemm_bt(const unsigned short* __restrict__ A,
                                               const unsigned short* __restrict__ Bt,
                                               const float* __restrict__ bias,
                                               void* __restrict__ Cv,
                                               int M, int N, int K) {
  __shared__ unsigned short Al[2][128 * 32];
  __shared__ unsigned short Bl[2][128 * 32];
  const int tid = threadIdx.x;
  const int wave = tid >> 6, lane = tid & 63;
  const int bm = blockIdx.y, bn = blockIdx.x;
  const int lr = lane & 15;
  const int lk16 = (lane >> 4) * 16;           // byte offset of k-chunk
  const int wr = (wave >> 1) * 64, wc = (wave & 1) * 64;
  const int nk = K >> 5;

  // staging: wave covers 32 rows (2 issues of 16); lane -> row (l>>2), 16B col (l&3)
  const int srow = wave * 32 + (lane >> 2);
  const int scolb = (lane & 3) * 16;
  const char* gA = (const char*)A + ((size_t)(bm * 128 + srow) * K) * 2 + scolb;
  const char* gB = (const char*)Bt + ((size_t)(bn * 128 + srow) * K) * 2 + scolb;
  const size_t rowstep = (size_t)K * 2 * 16;   // 16 rows forward

  f32x4 acc[4][4] = {};

  auto stage = [&](int buf, int kt) {
    const size_t ko = (size_t)kt * 64;
    char* la = (char*)&Al[buf][0] + wave * 2048;  // wave-uniform LDS base
    char* lb = (char*)&Bl[buf][0] + wave * 2048;
    gld_lds16(gA + ko, la);
    gld_lds16(gA + ko + rowstep, la + 1024);
    gld_lds16(gB + ko, lb);
    gld_lds16(gB + ko + rowstep, lb + 1024);
  };

  stage(0, 0);
  for (int kt = 0; kt < nk; ++kt) {
    __syncthreads();                       // drains vmcnt -> current buf ready
    if (kt + 1 < nk) stage((kt + 1) & 1, kt + 1);
    const char* ab = (const char*)&Al[kt & 1][0];
    const char* bb = (const char*)&Bl[kt & 1][0];
    bf16x8 af[4], bfr[4];
#pragma unroll
    for (int m = 0; m < 4; m++)
      af[m] = *(const bf16x8*)(ab + (wr + m * 16 + lr) * 64 + lk16);
#pragma unroll
    for (int n = 0; n < 4; n++)
      bfr[n] = *(const bf16x8*)(bb + (wc + n * 16 + lr) * 64 + lk16);
#pragma unroll
    for (int m = 0; m < 4; m++)
#pragma unroll
      for (int n = 0; n < 4; n++)
        acc[m][n] = mfma16(af[m], bfr[n], acc[m][n]);
  }

#pragma unroll
  for (int n = 0; n < 4; n++) {
    int col = bn * 128 + wc + n * 16 + lr;
    float bv = bias[col];
#pragma unroll
    for (int m = 0; m < 4; m++) {
      int row0 = bm * 128 + wr + m * 16 + (lane >> 4) * 4;
#pragma unroll
      for (int r = 0; r < 4; r++) {
        float v = acc[m][n][r] + bv;
        if (OUT_BF16)
          ((unsigned short*)Cv)[(size_t)(row0 + r) * N + col] = f2bf(v);
        else
          ((float*)Cv)[(size_t)(row0 + r) * N + col] = v;
      }
    }
  }
}

// ---------------------------------------------------------------------------
// Flash attention: Q[4096][1024] bf16, KV[4096][2048] bf16 (K cols 0..1023,
// V cols 1024..2047). One block = one (b,h) x 64 q-rows; 4 waves x 16 rows.
// Writes bf16 into fused[4096][2048] at column base outColBase.
// ---------------------------------------------------------------------------
template <bool CLAMP>
__global__ __launch_bounds__(256) void attn_kernel(const unsigned short* __restrict__ Q,
                                                   const unsigned short* __restrict__ KV,
                                                   unsigned short* __restrict__ Out,
                                                   int outColBase) {
  __shared__ unsigned short Kl[128 * 64];       // [key][hd], swizzled
  __shared__ unsigned short Vt[64 * 128];       // [hd][key], swizzled
  __shared__ unsigned short Pl[4][16 * 128];    // per-wave P, swizzled

  const int tid = threadIdx.x;
  const int wave = tid >> 6, lane = tid & 63;
  const int b = blockIdx.y >> 4, h = blockIdx.y & 15;
  const int qt = blockIdx.x;
  const int lr = lane & 15;
  const int lk16 = (lane >> 4) * 16;
  const int g4 = lane >> 4;

  // Q fragments in registers (reused over all KV tiles)
  const size_t qrow = (size_t)b * 1024 + qt * 64 + wave * 16 + lr;
  const char* qp = (const char*)(Q + qrow * 1024 + h * 64);
  const bf16x8 qa0 = *(const bf16x8*)(qp + lk16);        // hd 0..31 chunk
  const bf16x8 qa1 = *(const bf16x8*)(qp + 64 + lk16);   // hd 32..63 chunk

  f32x4 acc[4] = {};
  float mrun[4], lsum[4];
#pragma unroll
  for (int r = 0; r < 4; r++) { mrun[r] = -1e30f; lsum[r] = 0.f; }

  char* pb = (char*)&Pl[wave][0];
  const char* kvbase = (const char*)(KV + ((size_t)b * 1024) * 2048 + h * 64);

  for (int kt = 0; kt < 8; ++kt) {
    if (kt) __syncthreads();   // everyone done reading Kl/Vt from prev tile
    // stage K tile [128][64] bf16, XOR-swizzled rows
#pragma unroll
    for (int p2 = 0; p2 < 4; p2++) {
      int chunk = tid + p2 * 256;            // 0..1023
      int r = chunk >> 3, cb = (chunk & 7) * 16;
      uint4 v = *(const uint4*)(kvbase + (size_t)(kt * 128 + r) * 4096 + cb);
      *(uint4*)((char*)Kl + ((r * 128 + cb) ^ ((r & 7) << 4))) = v;
    }
    // stage V^T tile [64][128] bf16 (transpose via scalar writes), swizzled
#pragma unroll
    for (int p2 = 0; p2 < 4; p2++) {
      int chunk = tid + p2 * 256;
      int key = chunk >> 3, d0 = (chunk & 7) * 8;
      uint4 v = *(const uint4*)(kvbase + 2048 + (size_t)(kt * 128 + key) * 4096 + d0 * 2);
      const unsigned short* hv = (const unsigned short*)&v;
#pragma unroll
      for (int j = 0; j < 8; j++) {
        int d = d0 + j;
        *(unsigned short*)((char*)Vt + ((d * 256 + key * 2) ^ ((d & 7) << 4))) = hv[j];
      }
    }
    __syncthreads();

    // QK^T: scores for 16 q-rows x 128 keys per wave
    f32x4 st[8];
#pragma unroll
    for (int t8 = 0; t8 < 8; t8++) {
      int krow = t8 * 16 + lr;
      int sw = (krow & 7) << 4;
      const char* kr = (const char*)Kl + krow * 128;
      bf16x8 kb0 = *(const bf16x8*)(kr + ((0 + lk16) ^ sw));
      bf16x8 kb1 = *(const bf16x8*)(kr + ((64 + lk16) ^ sw));
      f32x4 s = {};
      s = mfma16(qa0, kb0, s);
      s = mfma16(qa1, kb1, s);
#pragma unroll
      for (int r = 0; r < 4; r++) {
        float v = s[r] * 0.125f;
        if (CLAMP) v = fminf(fmaxf(v, -100.f), 100.f);
        s[r] = v;
      }
      st[t8] = s;
    }

    // online softmax (rows g4*4+r; keys spread over 16-lane group + st[8])
#pragma unroll
    for (int r = 0; r < 4; r++) {
      float mx = st[0][r];
#pragma unroll
      for (int t8 = 1; t8 < 8; t8++) mx = fmaxf(mx, st[t8][r]);
#pragma unroll
      for (int off = 1; off < 16; off <<= 1) mx = fmaxf(mx, __shfl_xor(mx, off, 64));
      float mnew = fmaxf(mrun[r], mx);
      float al = __expf(mrun[r] - mnew);
      float sum = 0.f;
#pragma unroll
      for (int t8 = 0; t8 < 8; t8++) {
        float pv = __expf(st[t8][r] - mnew);
        st[t8][r] = pv;
        sum += pv;
      }
#pragma unroll
      for (int off = 1; off < 16; off <<= 1) sum += __shfl_xor(sum, off, 64);
      lsum[r] = lsum[r] * al + sum;
      mrun[r] = mnew;
#pragma unroll
      for (int n = 0; n < 4; n++) acc[n][r] *= al;
    }

    // write P (bf16) to per-wave LDS, swizzled
#pragma unroll
    for (int t8 = 0; t8 < 8; t8++) {
      int key = t8 * 16 + lr;
#pragma unroll
      for (int r = 0; r < 4; r++) {
        int prow = g4 * 4 + r;
        *(unsigned short*)(pb + ((prow * 256 + key * 2) ^ ((prow & 7) << 4))) =
            f2bf(st[t8][r]);
      }
    }
    __syncthreads();   // safety: P writes visible to all lanes of the wave

    // PV: O += P[16x128] @ V[128x64]
    bf16x8 pa[4];
#pragma unroll
    for (int kc = 0; kc < 4; kc++)
      pa[kc] = *(const bf16x8*)(pb + ((lr * 256 + kc * 64 + lk16) ^ ((lr & 7) << 4)));
#pragma unroll
    for (int n = 0; n < 4; n++) {
      int vr = n * 16 + lr;
      int sw = (vr & 7) << 4;
      const char* vp = (const char*)Vt + vr * 256;
#pragma unroll
      for (int kc = 0; kc < 4; kc++) {
        bf16x8 vb = *(const bf16x8*)(vp + ((kc * 64 + lk16) ^ sw));
        acc[n] = mfma16(pa[kc], vb, acc[n]);
      }
    }
  }

  // epilogue: O / l -> bf16 fused
  const size_t orow0 = (size_t)b * 1024 + qt * 64 + wave * 16 + g4 * 4;
#pragma unroll
  for (int n = 0; n < 4; n++) {
    int col = outColBase + h * 64 + n * 16 + lr;
#pragma unroll
    for (int r = 0; r < 4; r++) {
      float o = acc[n][r] / lsum[r];
      Out[(orow0 + r) * 2048 + col] = f2bf(o);
    }
  }
}

// ---------------------------------------------------------------------------
// In-place LayerNorm over rows of 1024 fp32 (1 block = 1 row, 256 thr)
// ---------------------------------------------------------------------------
__global__ __launch_bounds__(256) void ln_inplace(float* __restrict__ io,
                                                  const float* __restrict__ gamma,
                                                  const float* __restrict__ beta) {
  __shared__ float red[8];
  int row = blockIdx.x, tid = threadIdx.x;
  float* p = io + (size_t)row * 1024;
  float4 x = ((const float4*)p)[tid];
  float s = x.x + x.y + x.z + x.w;
  float s2 = x.x * x.x + x.y * x.y + x.z * x.z + x.w * x.w;
#pragma unroll
  for (int off = 32; off; off >>= 1) {
    s += __shfl_down(s, off, 64);
    s2 += __shfl_down(s2, off, 64);
  }
  int wv = tid >> 6;
  if ((tid & 63) == 0) { red[wv] = s; red[4 + wv] = s2; }
  __syncthreads();
  if (tid == 0) {
    red[0] = red[0] + red[1] + red[2] + red[3];
    red[4] = red[4] + red[5] + red[6] + red[7];
  }
  __syncthreads();
  float mu = red[0] * (1.f / 1024.f);
  float var = red[4] * (1.f / 1024.f) - mu * mu;
  float inv = rsqrtf(var + 1e-5f);
  float4 g = ((const float4*)gamma)[tid];
  float4 bb = ((const float4*)beta)[tid];
  x.x = (x.x - mu) * inv * g.x + bb.x;
  x.y = (x.y - mu) * inv * g.y + bb.y;
  x.z = (x.z - mu) * inv * g.z + bb.z;
  x.w = (x.w - mu) * inv * g.w + bb.w;
  ((float4*)p)[tid] = x;
}

// ---------------------------------------------------------------------------
extern "C" void kernel_launch(void* const* d_in, const int* in_sizes, int n_in,
                              void* d_out, int out_size, void* d_ws, size_t ws_size,
                              hipStream_t stream) {
  (void)in_sizes; (void)n_in; (void)out_size; (void)ws_size;
  const float* image = (const float*)d_in[0];
  const float* wavef = (const float*)d_in[1];
  const float* Wq_i  = (const float*)d_in[2];
  const float* bq_i  = (const float*)d_in[3];
  const float* Wkv_w = (const float*)d_in[4];
  const float* bkv_w = (const float*)d_in[5];
  const float* Wq_w  = (const float*)d_in[6];
  const float* bq_w  = (const float*)d_in[7];
  const float* Wkv_i = (const float*)d_in[8];
  const float* bkv_i = (const float*)d_in[9];
  const float* Wp    = (const float*)d_in[10];
  const float* bp    = (const float*)d_in[11];
  const float* gamma = (const float*)d_in[12];
  const float* beta  = (const float*)d_in[13];
  float* out = (float*)d_out;

  // workspace layout (80 MiB). fused (16MB) aliases Xi+Xw, safe because
  // attention (writes fused) runs after all projection GEMMs (read Xi/Xw).
  char* ws = (char*)d_ws;
  unsigned short* Xi = (unsigned short*)ws;                       // 8 MiB
  unsigned short* Xw = (unsigned short*)ws + 4096ull * 1024;      // 8 MiB
  unsigned short* fused = (unsigned short*)ws;                    // 16 MiB alias
  size_t off = 16ull << 20;
  auto take = [&](size_t bytes) { void* p = ws + off; off += bytes; return p; };
  unsigned short* Wt_qi  = (unsigned short*)take(2ull << 20);
  unsigned short* Wt_kvw = (unsigned short*)take(4ull << 20);
  unsigned short* Wt_qw  = (unsigned short*)take(2ull << 20);
  unsigned short* Wt_kvi = (unsigned short*)take(4ull << 20);
  unsigned short* Wt_p   = (unsigned short*)take(4ull << 20);
  unsigned short* q_s    = (unsigned short*)take(8ull << 20);
  unsigned short* q_f    = (unsigned short*)take(8ull << 20);
  unsigned short* kv_w   = (unsigned short*)take(16ull << 20);
  unsigned short* kv_s   = (unsigned short*)take(16ull << 20);

  // 1) convert activations to bf16
  cvt_kernel<<<4096, 256, 0, stream>>>(image, Xi);
  cvt_kernel<<<4096, 256, 0, stream>>>(wavef, Xw);
  // 2) transpose+convert weights to [N][K] bf16
  transpose_cvt<<<dim3(32, 32), 256, 0, stream>>>(Wq_i,  Wt_qi,  1024, 1024);
  transpose_cvt<<<dim3(64, 32), 256, 0, stream>>>(Wkv_w, Wt_kvw, 1024, 2048);
  transpose_cvt<<<dim3(32, 32), 256, 0, stream>>>(Wq_w,  Wt_qw,  1024, 1024);
  transpose_cvt<<<dim3(64, 32), 256, 0, stream>>>(Wkv_i, Wt_kvi, 1024, 2048);
  transpose_cvt<<<dim3(32, 64), 256, 0, stream>>>(Wp,    Wt_p,   2048, 1024);
  // 3) projections
  gemm_bt<true><<<dim3(8, 32),  256, 0, stream>>>(Xi, Wt_qi,  bq_i,  q_s,  4096, 1024, 1024);
  gemm_bt<true><<<dim3(16, 32), 256, 0, stream>>>(Xw, Wt_kvw, bkv_w, kv_w, 4096, 2048, 1024);
  gemm_bt<true><<<dim3(8, 32),  256, 0, stream>>>(Xw, Wt_qw,  bq_w,  q_f,  4096, 1024, 1024);
  gemm_bt<true><<<dim3(16, 32), 256, 0, stream>>>(Xi, Wt_kvi, bkv_i, kv_s, 4096, 2048, 1024);
  // 4) cross attention (image->waveform clamps scores; waveform->image doesn't)
  attn_kernel<true ><<<dim3(16, 64), 256, 0, stream>>>(q_s, kv_w, fused, 0);
  attn_kernel<false><<<dim3(16, 64), 256, 0, stream>>>(q_f, kv_s, fused, 1024);
  // 5) output projection (fp32 out) + 6) in-place LayerNorm
  gemm_bt<false><<<dim3(8, 32), 256, 0, stream>>>(fused, Wt_p, bp, out, 4096, 1024, 2048);
  ln_inplace<<<4096, 256, 0, stream>>>(out, gamma, beta);
}

// Round 4
// 302.544 us; speedup vs baseline: 1.1315x; 1.1315x over previous
//
#include <hip/hip_runtime.h>
#include <hip/hip_bf16.h>

#define DEVINL __device__ __forceinline__

typedef float f32x4 __attribute__((ext_vector_type(4)));
typedef __bf16 bf16x8 __attribute__((ext_vector_type(8)));

DEVINL void gld_lds16(const void* g, void* l) {
  __builtin_amdgcn_global_load_lds(
      (const __attribute__((address_space(1))) unsigned int*)g,
      (__attribute__((address_space(3))) unsigned int*)l, 16, 0, 0);
}

DEVINL unsigned short f2bf(float f) {
  __bf16 h = (__bf16)f;
  return __builtin_bit_cast(unsigned short, h);
}

DEVINL f32x4 mfma16(bf16x8 a, bf16x8 b, f32x4 c) {
  return __builtin_amdgcn_mfma_f32_16x16x32_bf16(a, b, c, 0, 0, 0);
}

// ---------------------------------------------------------------------------
// fp32 -> bf16 convert (4 elems/thread), fixed 4M elements (grid 4096 x 256)
// ---------------------------------------------------------------------------
__global__ __launch_bounds__(256) void cvt_kernel(const float* __restrict__ in,
                                                  unsigned short* __restrict__ outp) {
  int i = blockIdx.x * 256 + threadIdx.x;
  float4 v = ((const float4*)in)[i];
  ushort4 o;
  o.x = f2bf(v.x); o.y = f2bf(v.y); o.z = f2bf(v.z); o.w = f2bf(v.w);
  ((ushort4*)outp)[i] = o;
}

// ---------------------------------------------------------------------------
// W[K][N] fp32 -> Wt[N][K] bf16 (32x32 tiles)
// ---------------------------------------------------------------------------
__global__ __launch_bounds__(256) void transpose_cvt(const float* __restrict__ W,
                                                     unsigned short* __restrict__ Wt,
                                                     int K, int N) {
  __shared__ float t[32][33];
  int n0 = blockIdx.x * 32, k0 = blockIdx.y * 32;
  int tx = threadIdx.x & 31, ty = threadIdx.x >> 5;  // ty 0..7
#pragma unroll
  for (int i = 0; i < 4; i++)
    t[ty + i * 8][tx] = W[(size_t)(k0 + ty + i * 8) * N + n0 + tx];
  __syncthreads();
#pragma unroll
  for (int i = 0; i < 4; i++) {
    int n = ty + i * 8;
    Wt[(size_t)(n0 + n) * K + k0 + tx] = f2bf(t[tx][n]);
  }
}

// ---------------------------------------------------------------------------
// GEMM: C[M][N] = A[M][K] @ Bt[N][K]^T + bias ; A,Bt bf16 ; C bf16 or fp32
// 128x128 tile, BK=32, 4 waves, m97-style global_load_lds staging
// ---------------------------------------------------------------------------
template <bool OUT_BF16>
__global__ __launch_bounds__(256) void gemm_bt(const unsigned short* __restrict__ A,
                                               const unsigned short* __restrict__ Bt,
                                               const float* __restrict__ bias,
                                               void* __restrict__ Cv,
                                               int M, int N, int K) {
  __shared__ unsigned short Al[2][128 * 32];
  __shared__ unsigned short Bl[2][128 * 32];
  const int tid = threadIdx.x;
  const int wave = tid >> 6, lane = tid & 63;
  const int bm = blockIdx.y, bn = blockIdx.x;
  const int lr = lane & 15;
  const int lk16 = (lane >> 4) * 16;           // byte offset of k-chunk
  const int wr = (wave >> 1) * 64, wc = (wave & 1) * 64;
  const int nk = K >> 5;

  const int srow = wave * 32 + (lane >> 2);
  const int scolb = (lane & 3) * 16;
  const char* gA = (const char*)A + ((size_t)(bm * 128 + srow) * K) * 2 + scolb;
  const char* gB = (const char*)Bt + ((size_t)(bn * 128 + srow) * K) * 2 + scolb;
  const size_t rowstep = (size_t)K * 2 * 16;   // 16 rows forward

  f32x4 acc[4][4] = {};

  auto stage = [&](int buf, int kt) {
    const size_t ko = (size_t)kt * 64;
    char* la = (char*)&Al[buf][0] + wave * 2048;  // wave-uniform LDS base
    char* lb = (char*)&Bl[buf][0] + wave * 2048;
    gld_lds16(gA + ko, la);
    gld_lds16(gA + ko + rowstep, la + 1024);
    gld_lds16(gB + ko, lb);
    gld_lds16(gB + ko + rowstep, lb + 1024);
  };

  stage(0, 0);
  for (int kt = 0; kt < nk; ++kt) {
    __syncthreads();
    if (kt + 1 < nk) stage((kt + 1) & 1, kt + 1);
    const char* ab = (const char*)&Al[kt & 1][0];
    const char* bb = (const char*)&Bl[kt & 1][0];
    bf16x8 af[4], bfr[4];
#pragma unroll
    for (int m = 0; m < 4; m++)
      af[m] = *(const bf16x8*)(ab + (wr + m * 16 + lr) * 64 + lk16);
#pragma unroll
    for (int n = 0; n < 4; n++)
      bfr[n] = *(const bf16x8*)(bb + (wc + n * 16 + lr) * 64 + lk16);
#pragma unroll
    for (int m = 0; m < 4; m++)
#pragma unroll
      for (int n = 0; n < 4; n++)
        acc[m][n] = mfma16(af[m], bfr[n], acc[m][n]);
  }

#pragma unroll
  for (int n = 0; n < 4; n++) {
    int col = bn * 128 + wc + n * 16 + lr;
    float bv = bias[col];
#pragma unroll
    for (int m = 0; m < 4; m++) {
      int row0 = bm * 128 + wr + m * 16 + (lane >> 4) * 4;
#pragma unroll
      for (int r = 0; r < 4; r++) {
        float v = acc[m][n][r] + bv;
        if (OUT_BF16)
          ((unsigned short*)Cv)[(size_t)(row0 + r) * N + col] = f2bf(v);
        else
          ((float*)Cv)[(size_t)(row0 + r) * N + col] = v;
      }
    }
  }
}

// ---------------------------------------------------------------------------
// KV projection GEMM: same compute as gemm_bt (M=4096,N=2048,K=1024) but the
// epilogue splits: cols 0..1023 -> K buffer [4096][1024] (bf16, row-major);
// cols 1024..2047 -> V^T global [b*16+h][64 d][1024 s] (bf16), packed ushort4
// along s (the 4 accumulator rows are consecutive s).
// ---------------------------------------------------------------------------
__global__ __launch_bounds__(256) void gemm_kv_split(const unsigned short* __restrict__ A,
                                                     const unsigned short* __restrict__ Bt,
                                                     const float* __restrict__ bias,
                                                     unsigned short* __restrict__ Kbuf,
                                                     unsigned short* __restrict__ VtG) {
  const int Kdim = 1024, N = 2048;
  __shared__ unsigned short Al[2][128 * 32];
  __shared__ unsigned short Bl[2][128 * 32];
  const int tid = threadIdx.x;
  const int wave = tid >> 6, lane = tid & 63;
  const int bm = blockIdx.y, bn = blockIdx.x;
  const int lr = lane & 15;
  const int lk16 = (lane >> 4) * 16;
  const int wr = (wave >> 1) * 64, wc = (wave & 1) * 64;
  const int nk = Kdim >> 5;

  const int srow = wave * 32 + (lane >> 2);
  const int scolb = (lane & 3) * 16;
  const char* gA = (const char*)A + ((size_t)(bm * 128 + srow) * Kdim) * 2 + scolb;
  const char* gB = (const char*)Bt + ((size_t)(bn * 128 + srow) * Kdim) * 2 + scolb;
  const size_t rowstep = (size_t)Kdim * 2 * 16;

  f32x4 acc[4][4] = {};

  auto stage = [&](int buf, int kt) {
    const size_t ko = (size_t)kt * 64;
    char* la = (char*)&Al[buf][0] + wave * 2048;
    char* lb = (char*)&Bl[buf][0] + wave * 2048;
    gld_lds16(gA + ko, la);
    gld_lds16(gA + ko + rowstep, la + 1024);
    gld_lds16(gB + ko, lb);
    gld_lds16(gB + ko + rowstep, lb + 1024);
  };

  stage(0, 0);
  for (int kt = 0; kt < nk; ++kt) {
    __syncthreads();
    if (kt + 1 < nk) stage((kt + 1) & 1, kt + 1);
    const char* ab = (const char*)&Al[kt & 1][0];
    const char* bb = (const char*)&Bl[kt & 1][0];
    bf16x8 af[4], bfr[4];
#pragma unroll
    for (int m = 0; m < 4; m++)
      af[m] = *(const bf16x8*)(ab + (wr + m * 16 + lr) * 64 + lk16);
#pragma unroll
    for (int n = 0; n < 4; n++)
      bfr[n] = *(const bf16x8*)(bb + (wc + n * 16 + lr) * 64 + lk16);
#pragma unroll
    for (int m = 0; m < 4; m++)
#pragma unroll
      for (int n = 0; n < 4; n++)
        acc[m][n] = mfma16(af[m], bfr[n], acc[m][n]);
  }

#pragma unroll
  for (int n = 0; n < 4; n++) {
    int col = bn * 128 + wc + n * 16 + lr;
    float bv = bias[col];
#pragma unroll
    for (int m = 0; m < 4; m++) {
      int row0 = bm * 128 + wr + m * 16 + (lane >> 4) * 4;
      if (col < 1024) {
#pragma unroll
        for (int r = 0; r < 4; r++)
          Kbuf[(size_t)(row0 + r) * 1024 + col] = f2bf(acc[m][n][r] + bv);
      } else {
        int h = (col - 1024) >> 6, d = (col - 1024) & 63;
        int b = row0 >> 10, s = row0 & 1023;   // 4 rows stay within one b
        ushort4 pk;
        pk.x = f2bf(acc[m][n][0] + bv);
        pk.y = f2bf(acc[m][n][1] + bv);
        pk.z = f2bf(acc[m][n][2] + bv);
        pk.w = f2bf(acc[m][n][3] + bv);
        *(ushort4*)&VtG[((size_t)(b * 16 + h) * 64 + d) * 1024 + s] = pk;
      }
    }
  }
  (void)N;
}

// ---------------------------------------------------------------------------
// Flash attention. Q[4096][1024] bf16; Kg [4096][1024] bf16 (per-head cols);
// VtG [64 bh][64 d][1024 s] bf16 (pre-transposed V). One block = (b,h) x 64
// q-rows; 4 waves x 16 rows. K and V^T staged via global_load_lds with
// pre-swizzled SOURCE addresses (LDS dest linear, read-side XOR matches).
// ---------------------------------------------------------------------------
template <bool CLAMP>
__global__ __launch_bounds__(256) void attn_kernel(const unsigned short* __restrict__ Q,
                                                   const unsigned short* __restrict__ Kg,
                                                   const unsigned short* __restrict__ VtG,
                                                   unsigned short* __restrict__ Out,
                                                   int outColBase) {
  __shared__ unsigned short Kl[128 * 64];       // [key][hd], swizzled content
  __shared__ unsigned short Vt[64 * 128];       // [hd][key], swizzled content
  __shared__ unsigned short Pl[4][16 * 128];    // per-wave P, swizzled

  const int tid = threadIdx.x;
  const int wave = tid >> 6, lane = tid & 63;
  const int b = blockIdx.y >> 4, h = blockIdx.y & 15;
  const int qt = blockIdx.x;
  const int lr = lane & 15;
  const int lk16 = (lane >> 4) * 16;
  const int g4 = lane >> 4;

  // Q fragments in registers (reused over all KV tiles)
  const size_t qrow = (size_t)b * 1024 + qt * 64 + wave * 16 + lr;
  const char* qp = (const char*)(Q + qrow * 1024 + h * 64);
  const bf16x8 qa0 = *(const bf16x8*)(qp + lk16);        // hd 0..31 chunk
  const bf16x8 qa1 = *(const bf16x8*)(qp + 64 + lk16);   // hd 32..63 chunk

  f32x4 acc[4] = {};
  float mrun[4], lsum[4];
#pragma unroll
  for (int r = 0; r < 4; r++) { mrun[r] = -1e30f; lsum[r] = 0.f; }

  char* pb = (char*)&Pl[wave][0];
  // K source: row (b*1024 + kt*128 + r), byte col h*128 + swizzled 0..127
  const char* kbase = (const char*)Kg + (size_t)b * 1024 * 2048 + h * 128;
  // V^T source: row (bh*64 + d) of 2048B, byte col kt*256 + swizzled 0..255
  const char* vbase = (const char*)VtG + (size_t)(b * 16 + h) * 64 * 2048;

  // per-lane staging coords (constant over kt)
  const int kc_r = (tid * 4) >> 3;                 // not used; clarity below
  (void)kc_r;

  for (int kt = 0; kt < 8; ++kt) {
    if (kt) __syncthreads();   // everyone done reading Kl/Vt from prev tile
    // stage K tile [128 keys][64 hd]: 1024 x 16B chunks, src pre-swizzled
#pragma unroll
    for (int p2 = 0; p2 < 4; p2++) {
      int chunk = tid + p2 * 256;                  // 0..1023
      int r = chunk >> 3, cb = (chunk & 7) * 16;   // row, 16B col
      const char* src = kbase + (size_t)(kt * 128 + r) * 2048 + (cb ^ ((r & 7) << 4));
      char* dst = (char*)Kl + (p2 * 256 + wave * 64) * 16;  // wave-uniform
      gld_lds16(src, dst);
    }
    // stage V^T tile [64 hd][128 keys]: 1024 x 16B chunks, src pre-swizzled
#pragma unroll
    for (int p2 = 0; p2 < 4; p2++) {
      int chunk = tid + p2 * 256;
      int d = chunk >> 4, ko = (chunk & 15) * 16;
      const char* src = vbase + (size_t)d * 2048 + kt * 256 + (ko ^ ((d & 7) << 4));
      char* dst = (char*)Vt + (p2 * 256 + wave * 64) * 16;  // wave-uniform
      gld_lds16(src, dst);
    }
    __syncthreads();

    // QK^T: scores for 16 q-rows x 128 keys per wave
    f32x4 st[8];
#pragma unroll
    for (int t8 = 0; t8 < 8; t8++) {
      int krow = t8 * 16 + lr;
      int sw = (krow & 7) << 4;
      const char* kr = (const char*)Kl + krow * 128;
      bf16x8 kb0 = *(const bf16x8*)(kr + ((0 + lk16) ^ sw));
      bf16x8 kb1 = *(const bf16x8*)(kr + ((64 + lk16) ^ sw));
      f32x4 s = {};
      s = mfma16(qa0, kb0, s);
      s = mfma16(qa1, kb1, s);
#pragma unroll
      for (int r = 0; r < 4; r++) {
        float v = s[r] * 0.125f;
        if (CLAMP) v = fminf(fmaxf(v, -100.f), 100.f);
        s[r] = v;
      }
      st[t8] = s;
    }

    // online softmax (rows g4*4+r; keys spread over 16-lane group + st[8])
#pragma unroll
    for (int r = 0; r < 4; r++) {
      float mx = st[0][r];
#pragma unroll
      for (int t8 = 1; t8 < 8; t8++) mx = fmaxf(mx, st[t8][r]);
#pragma unroll
      for (int off = 1; off < 16; off <<= 1) mx = fmaxf(mx, __shfl_xor(mx, off, 64));
      float mnew = fmaxf(mrun[r], mx);
      float al = __expf(mrun[r] - mnew);
      float sum = 0.f;
#pragma unroll
      for (int t8 = 0; t8 < 8; t8++) {
        float pv = __expf(st[t8][r] - mnew);
        st[t8][r] = pv;
        sum += pv;
      }
#pragma unroll
      for (int off = 1; off < 16; off <<= 1) sum += __shfl_xor(sum, off, 64);
      lsum[r] = lsum[r] * al + sum;
      mrun[r] = mnew;
#pragma unroll
      for (int n = 0; n < 4; n++) acc[n][r] *= al;
    }

    // write P (bf16) to per-wave LDS, swizzled
#pragma unroll
    for (int t8 = 0; t8 < 8; t8++) {
      int key = t8 * 16 + lr;
#pragma unroll
      for (int r = 0; r < 4; r++) {
        int prow = g4 * 4 + r;
        *(unsigned short*)(pb + ((prow * 256 + key * 2) ^ ((prow & 7) << 4))) =
            f2bf(st[t8][r]);
      }
    }
    __syncthreads();

    // PV: O += P[16x128] @ V[128x64]
    bf16x8 pa[4];
#pragma unroll
    for (int kc = 0; kc < 4; kc++)
      pa[kc] = *(const bf16x8*)(pb + ((lr * 256 + kc * 64 + lk16) ^ ((lr & 7) << 4)));
#pragma unroll
    for (int n = 0; n < 4; n++) {
      int vr = n * 16 + lr;
      int sw = (vr & 7) << 4;
      const char* vp = (const char*)Vt + vr * 256;
#pragma unroll
      for (int kc = 0; kc < 4; kc++) {
        bf16x8 vb = *(const bf16x8*)(vp + ((kc * 64 + lk16) ^ sw));
        acc[n] = mfma16(pa[kc], vb, acc[n]);
      }
    }
  }

  // epilogue: O / l -> bf16 fused
  const size_t orow0 = (size_t)b * 1024 + qt * 64 + wave * 16 + g4 * 4;
#pragma unroll
  for (int n = 0; n < 4; n++) {
    int col = outColBase + h * 64 + n * 16 + lr;
#pragma unroll
    for (int r = 0; r < 4; r++) {
      float o = acc[n][r] / lsum[r];
      Out[(orow0 + r) * 2048 + col] = f2bf(o);
    }
  }
}

// ---------------------------------------------------------------------------
// In-place LayerNorm over rows of 1024 fp32 (1 block = 1 row, 256 thr)
// ---------------------------------------------------------------------------
__global__ __launch_bounds__(256) void ln_inplace(float* __restrict__ io,
                                                  const float* __restrict__ gamma,
                                                  const float* __restrict__ beta) {
  __shared__ float red[8];
  int row = blockIdx.x, tid = threadIdx.x;
  float* p = io + (size_t)row * 1024;
  float4 x = ((const float4*)p)[tid];
  float s = x.x + x.y + x.z + x.w;
  float s2 = x.x * x.x + x.y * x.y + x.z * x.z + x.w * x.w;
#pragma unroll
  for (int off = 32; off; off >>= 1) {
    s += __shfl_down(s, off, 64);
    s2 += __shfl_down(s2, off, 64);
  }
  int wv = tid >> 6;
  if ((tid & 63) == 0) { red[wv] = s; red[4 + wv] = s2; }
  __syncthreads();
  if (tid == 0) {
    red[0] = red[0] + red[1] + red[2] + red[3];
    red[4] = red[4] + red[5] + red[6] + red[7];
  }
  __syncthreads();
  float mu = red[0] * (1.f / 1024.f);
  float var = red[4] * (1.f / 1024.f) - mu * mu;
  float inv = rsqrtf(var + 1e-5f);
  float4 g = ((const float4*)gamma)[tid];
  float4 bb = ((const float4*)beta)[tid];
  x.x = (x.x - mu) * inv * g.x + bb.x;
  x.y = (x.y - mu) * inv * g.y + bb.y;
  x.z = (x.z - mu) * inv * g.z + bb.z;
  x.w = (x.w - mu) * inv * g.w + bb.w;
  ((float4*)p)[tid] = x;
}

// ---------------------------------------------------------------------------
extern "C" void kernel_launch(void* const* d_in, const int* in_sizes, int n_in,
                              void* d_out, int out_size, void* d_ws, size_t ws_size,
                              hipStream_t stream) {
  (void)in_sizes; (void)n_in; (void)out_size; (void)ws_size;
  const float* image = (const float*)d_in[0];
  const float* wavef = (const float*)d_in[1];
  const float* Wq_i  = (const float*)d_in[2];
  const float* bq_i  = (const float*)d_in[3];
  const float* Wkv_w = (const float*)d_in[4];
  const float* bkv_w = (const float*)d_in[5];
  const float* Wq_w  = (const float*)d_in[6];
  const float* bq_w  = (const float*)d_in[7];
  const float* Wkv_i = (const float*)d_in[8];
  const float* bkv_i = (const float*)d_in[9];
  const float* Wp    = (const float*)d_in[10];
  const float* bp    = (const float*)d_in[11];
  const float* gamma = (const float*)d_in[12];
  const float* beta  = (const float*)d_in[13];
  float* out = (float*)d_out;

  // workspace layout (80 MiB). fused (16MB) aliases Xi+Xw, safe because
  // attention (writes fused) runs after all projection GEMMs (read Xi/Xw).
  char* ws = (char*)d_ws;
  unsigned short* Xi = (unsigned short*)ws;                       // 8 MiB
  unsigned short* Xw = (unsigned short*)ws + 4096ull * 1024;      // 8 MiB
  unsigned short* fused = (unsigned short*)ws;                    // 16 MiB alias
  size_t off = 16ull << 20;
  auto take = [&](size_t bytes) { void* p = ws + off; off += bytes; return p; };
  unsigned short* Wt_qi  = (unsigned short*)take(2ull << 20);
  unsigned short* Wt_kvw = (unsigned short*)take(4ull << 20);
  unsigned short* Wt_qw  = (unsigned short*)take(2ull << 20);
  unsigned short* Wt_kvi = (unsigned short*)take(4ull << 20);
  unsigned short* Wt_p   = (unsigned short*)take(4ull << 20);
  unsigned short* q_s    = (unsigned short*)take(8ull << 20);
  unsigned short* q_f    = (unsigned short*)take(8ull << 20);
  unsigned short* kvK_w  = (unsigned short*)take(8ull << 20);   // K half, wav
  unsigned short* VtG_w  = (unsigned short*)take(8ull << 20);   // V^T, wav
  unsigned short* kvK_s  = (unsigned short*)take(8ull << 20);   // K half, img
  unsigned short* VtG_s  = (unsigned short*)take(8ull << 20);   // V^T, img

  // 1) convert activations to bf16
  cvt_kernel<<<4096, 256, 0, stream>>>(image, Xi);
  cvt_kernel<<<4096, 256, 0, stream>>>(wavef, Xw);
  // 2) transpose+convert weights to [N][K] bf16
  transpose_cvt<<<dim3(32, 32), 256, 0, stream>>>(Wq_i,  Wt_qi,  1024, 1024);
  transpose_cvt<<<dim3(64, 32), 256, 0, stream>>>(Wkv_w, Wt_kvw, 1024, 2048);
  transpose_cvt<<<dim3(32, 32), 256, 0, stream>>>(Wq_w,  Wt_qw,  1024, 1024);
  transpose_cvt<<<dim3(64, 32), 256, 0, stream>>>(Wkv_i, Wt_kvi, 1024, 2048);
  transpose_cvt<<<dim3(32, 64), 256, 0, stream>>>(Wp,    Wt_p,   2048, 1024);
  // 3) projections (KV GEMMs split: K row-major + V pre-transposed)
  gemm_bt<true><<<dim3(8, 32),  256, 0, stream>>>(Xi, Wt_qi, bq_i, q_s, 4096, 1024, 1024);
  gemm_kv_split<<<dim3(16, 32), 256, 0, stream>>>(Xw, Wt_kvw, bkv_w, kvK_w, VtG_w);
  gemm_bt<true><<<dim3(8, 32),  256, 0, stream>>>(Xw, Wt_qw, bq_w, q_f, 4096, 1024, 1024);
  gemm_kv_split<<<dim3(16, 32), 256, 0, stream>>>(Xi, Wt_kvi, bkv_i, kvK_s, VtG_s);
  // 4) cross attention (image->waveform clamps scores; waveform->image doesn't)
  attn_kernel<true ><<<dim3(16, 64), 256, 0, stream>>>(q_s, kvK_w, VtG_w, fused, 0);
  attn_kernel<false><<<dim3(16, 64), 256, 0, stream>>>(q_f, kvK_s, VtG_s, fused, 1024);
  // 5) output projection (fp32 out) + 6) in-place LayerNorm
  gemm_bt<false><<<dim3(8, 32), 256, 0, stream>>>(fused, Wt_p, bp, out, 4096, 1024, 2048);
  ln_inplace<<<4096, 256, 0, stream>>>(out, gamma, beta);
}

// Round 5
// 295.622 us; speedup vs baseline: 1.1580x; 1.0234x over previous
//
#include <hip/hip_runtime.h>
#include <hip/hip_bf16.h>

#define DEVINL __device__ __forceinline__

typedef float f32x4 __attribute__((ext_vector_type(4)));
typedef __bf16 bf16x8 __attribute__((ext_vector_type(8)));

DEVINL void gld_lds16(const void* g, void* l) {
  __builtin_amdgcn_global_load_lds(
      (const __attribute__((address_space(1))) unsigned int*)g,
      (__attribute__((address_space(3))) unsigned int*)l, 16, 0, 0);
}

DEVINL unsigned short f2bf(float f) {
  __bf16 h = (__bf16)f;
  return __builtin_bit_cast(unsigned short, h);
}

DEVINL f32x4 mfma16(bf16x8 a, bf16x8 b, f32x4 c) {
  return __builtin_amdgcn_mfma_f32_16x16x32_bf16(a, b, c, 0, 0, 0);
}

// ---------------------------------------------------------------------------
// fp32 -> bf16 convert (4 elems/thread), fixed 4M elements (grid 4096 x 256)
// ---------------------------------------------------------------------------
__global__ __launch_bounds__(256) void cvt_kernel(const float* __restrict__ in,
                                                  unsigned short* __restrict__ outp) {
  int i = blockIdx.x * 256 + threadIdx.x;
  float4 v = ((const float4*)in)[i];
  ushort4 o;
  o.x = f2bf(v.x); o.y = f2bf(v.y); o.z = f2bf(v.z); o.w = f2bf(v.w);
  ((ushort4*)outp)[i] = o;
}

// ---------------------------------------------------------------------------
// W[K][N] fp32 -> Wt[N][K] bf16 (32x32 tiles)
// ---------------------------------------------------------------------------
__global__ __launch_bounds__(256) void transpose_cvt(const float* __restrict__ W,
                                                     unsigned short* __restrict__ Wt,
                                                     int K, int N) {
  __shared__ float t[32][33];
  int n0 = blockIdx.x * 32, k0 = blockIdx.y * 32;
  int tx = threadIdx.x & 31, ty = threadIdx.x >> 5;  // ty 0..7
#pragma unroll
  for (int i = 0; i < 4; i++)
    t[ty + i * 8][tx] = W[(size_t)(k0 + ty + i * 8) * N + n0 + tx];
  __syncthreads();
#pragma unroll
  for (int i = 0; i < 4; i++) {
    int n = ty + i * 8;
    Wt[(size_t)(n0 + n) * K + k0 + tx] = f2bf(t[tx][n]);
  }
}

// ---------------------------------------------------------------------------
// GEMM: C[M][N] = A[M][K] @ Bt[N][K]^T + bias ; A,Bt bf16 ; C bf16 or fp32
// 128x128 tile, BK=32, 4 waves, m97-style global_load_lds staging
// ---------------------------------------------------------------------------
template <bool OUT_BF16>
__global__ __launch_bounds__(256) void gemm_bt(const unsigned short* __restrict__ A,
                                               const unsigned short* __restrict__ Bt,
                                               const float* __restrict__ bias,
                                               void* __restrict__ Cv,
                                               int M, int N, int K) {
  __shared__ unsigned short Al[2][128 * 32];
  __shared__ unsigned short Bl[2][128 * 32];
  const int tid = threadIdx.x;
  const int wave = tid >> 6, lane = tid & 63;
  const int bm = blockIdx.y, bn = blockIdx.x;
  const int lr = lane & 15;
  const int lk16 = (lane >> 4) * 16;           // byte offset of k-chunk
  const int wr = (wave >> 1) * 64, wc = (wave & 1) * 64;
  const int nk = K >> 5;

  const int srow = wave * 32 + (lane >> 2);
  const int scolb = (lane & 3) * 16;
  const char* gA = (const char*)A + ((size_t)(bm * 128 + srow) * K) * 2 + scolb;
  const char* gB = (const char*)Bt + ((size_t)(bn * 128 + srow) * K) * 2 + scolb;
  const size_t rowstep = (size_t)K * 2 * 16;   // 16 rows forward

  f32x4 acc[4][4] = {};

  auto stage = [&](int buf, int kt) {
    const size_t ko = (size_t)kt * 64;
    char* la = (char*)&Al[buf][0] + wave * 2048;  // wave-uniform LDS base
    char* lb = (char*)&Bl[buf][0] + wave * 2048;
    gld_lds16(gA + ko, la);
    gld_lds16(gA + ko + rowstep, la + 1024);
    gld_lds16(gB + ko, lb);
    gld_lds16(gB + ko + rowstep, lb + 1024);
  };

  stage(0, 0);
  for (int kt = 0; kt < nk; ++kt) {
    __syncthreads();
    if (kt + 1 < nk) stage((kt + 1) & 1, kt + 1);
    const char* ab = (const char*)&Al[kt & 1][0];
    const char* bb = (const char*)&Bl[kt & 1][0];
    bf16x8 af[4], bfr[4];
#pragma unroll
    for (int m = 0; m < 4; m++)
      af[m] = *(const bf16x8*)(ab + (wr + m * 16 + lr) * 64 + lk16);
#pragma unroll
    for (int n = 0; n < 4; n++)
      bfr[n] = *(const bf16x8*)(bb + (wc + n * 16 + lr) * 64 + lk16);
#pragma unroll
    for (int m = 0; m < 4; m++)
#pragma unroll
      for (int n = 0; n < 4; n++)
        acc[m][n] = mfma16(af[m], bfr[n], acc[m][n]);
  }

#pragma unroll
  for (int n = 0; n < 4; n++) {
    int col = bn * 128 + wc + n * 16 + lr;
    float bv = bias[col];
#pragma unroll
    for (int m = 0; m < 4; m++) {
      int row0 = bm * 128 + wr + m * 16 + (lane >> 4) * 4;
#pragma unroll
      for (int r = 0; r < 4; r++) {
        float v = acc[m][n][r] + bv;
        if (OUT_BF16)
          ((unsigned short*)Cv)[(size_t)(row0 + r) * N + col] = f2bf(v);
        else
          ((float*)Cv)[(size_t)(row0 + r) * N + col] = v;
      }
    }
  }
}

// ---------------------------------------------------------------------------
// KV projection GEMM: epilogue splits cols 0..1023 -> K buffer [4096][1024];
// cols 1024..2047 -> V^T global [b*16+h][64 d][1024 s], packed ushort4 along s.
// ---------------------------------------------------------------------------
__global__ __launch_bounds__(256) void gemm_kv_split(const unsigned short* __restrict__ A,
                                                     const unsigned short* __restrict__ Bt,
                                                     const float* __restrict__ bias,
                                                     unsigned short* __restrict__ Kbuf,
                                                     unsigned short* __restrict__ VtG) {
  const int Kdim = 1024;
  __shared__ unsigned short Al[2][128 * 32];
  __shared__ unsigned short Bl[2][128 * 32];
  const int tid = threadIdx.x;
  const int wave = tid >> 6, lane = tid & 63;
  const int bm = blockIdx.y, bn = blockIdx.x;
  const int lr = lane & 15;
  const int lk16 = (lane >> 4) * 16;
  const int wr = (wave >> 1) * 64, wc = (wave & 1) * 64;
  const int nk = Kdim >> 5;

  const int srow = wave * 32 + (lane >> 2);
  const int scolb = (lane & 3) * 16;
  const char* gA = (const char*)A + ((size_t)(bm * 128 + srow) * Kdim) * 2 + scolb;
  const char* gB = (const char*)Bt + ((size_t)(bn * 128 + srow) * Kdim) * 2 + scolb;
  const size_t rowstep = (size_t)Kdim * 2 * 16;

  f32x4 acc[4][4] = {};

  auto stage = [&](int buf, int kt) {
    const size_t ko = (size_t)kt * 64;
    char* la = (char*)&Al[buf][0] + wave * 2048;
    char* lb = (char*)&Bl[buf][0] + wave * 2048;
    gld_lds16(gA + ko, la);
    gld_lds16(gA + ko + rowstep, la + 1024);
    gld_lds16(gB + ko, lb);
    gld_lds16(gB + ko + rowstep, lb + 1024);
  };

  stage(0, 0);
  for (int kt = 0; kt < nk; ++kt) {
    __syncthreads();
    if (kt + 1 < nk) stage((kt + 1) & 1, kt + 1);
    const char* ab = (const char*)&Al[kt & 1][0];
    const char* bb = (const char*)&Bl[kt & 1][0];
    bf16x8 af[4], bfr[4];
#pragma unroll
    for (int m = 0; m < 4; m++)
      af[m] = *(const bf16x8*)(ab + (wr + m * 16 + lr) * 64 + lk16);
#pragma unroll
    for (int n = 0; n < 4; n++)
      bfr[n] = *(const bf16x8*)(bb + (wc + n * 16 + lr) * 64 + lk16);
#pragma unroll
    for (int m = 0; m < 4; m++)
#pragma unroll
      for (int n = 0; n < 4; n++)
        acc[m][n] = mfma16(af[m], bfr[n], acc[m][n]);
  }

#pragma unroll
  for (int n = 0; n < 4; n++) {
    int col = bn * 128 + wc + n * 16 + lr;
    float bv = bias[col];
#pragma unroll
    for (int m = 0; m < 4; m++) {
      int row0 = bm * 128 + wr + m * 16 + (lane >> 4) * 4;
      if (col < 1024) {
#pragma unroll
        for (int r = 0; r < 4; r++)
          Kbuf[(size_t)(row0 + r) * 1024 + col] = f2bf(acc[m][n][r] + bv);
      } else {
        int h = (col - 1024) >> 6, d = (col - 1024) & 63;
        int b = row0 >> 10, s = row0 & 1023;   // 4 rows stay within one b
        ushort4 pk;
        pk.x = f2bf(acc[m][n][0] + bv);
        pk.y = f2bf(acc[m][n][1] + bv);
        pk.z = f2bf(acc[m][n][2] + bv);
        pk.w = f2bf(acc[m][n][3] + bv);
        *(ushort4*)&VtG[((size_t)(b * 16 + h) * 64 + d) * 1024 + s] = pk;
      }
    }
  }
}

// ---------------------------------------------------------------------------
// Flash attention, QBLK=128. Q[4096][1024] bf16; Kg [4096][1024] bf16;
// VtG [64 bh][64 d][1024 s] bf16 (pre-transposed V). One block = (b,h) x 128
// q-rows; 4 waves x 32 rows (2 groups of 16). K/V^T staged via global_load_lds
// with pre-swizzled SOURCE (LDS dest linear, read-side XOR matches).
// XCD remap: 8 blocks sharing one (b,h) land on the same XCD for KV L2 reuse.
// ---------------------------------------------------------------------------
template <bool CLAMP>
__global__ __launch_bounds__(256) void attn_kernel(const unsigned short* __restrict__ Q,
                                                   const unsigned short* __restrict__ Kg,
                                                   const unsigned short* __restrict__ VtG,
                                                   unsigned short* __restrict__ Out,
                                                   int outColBase) {
  __shared__ unsigned short Kl[128 * 64];        // [key][hd], swizzled content
  __shared__ unsigned short Vt[64 * 128];        // [hd][key], swizzled content
  __shared__ unsigned short Pl[4][2][16 * 128];  // per-wave, per-group P

  const int tid = threadIdx.x;
  const int wave = tid >> 6, lane = tid & 63;
  // XCD-aware remap (grid 8 x 64): qt = y&7, bh = x*8 + (y>>3) so all 8
  // q-tiles of one (b,h) share flat%8 (= same XCD on 8-XCD MI355X).
  const int qt = blockIdx.y & 7;
  const int bh = blockIdx.x * 8 + (blockIdx.y >> 3);
  const int b = bh >> 4, h = bh & 15;
  const int lr = lane & 15;
  const int lk16 = (lane >> 4) * 16;
  const int g4 = lane >> 4;

  // Q fragments in registers: 2 groups x 16 rows
  bf16x8 qa[2][2];
#pragma unroll
  for (int g = 0; g < 2; g++) {
    const size_t qrow = (size_t)b * 1024 + qt * 128 + wave * 32 + g * 16 + lr;
    const char* qp = (const char*)(Q + qrow * 1024 + h * 64);
    qa[g][0] = *(const bf16x8*)(qp + lk16);
    qa[g][1] = *(const bf16x8*)(qp + 64 + lk16);
  }

  f32x4 acc[2][4] = {};
  float mrun[2][4], lsum[2][4];
#pragma unroll
  for (int g = 0; g < 2; g++)
#pragma unroll
    for (int r = 0; r < 4; r++) { mrun[g][r] = -1e30f; lsum[g][r] = 0.f; }

  const char* kbase = (const char*)Kg + (size_t)b * 1024 * 2048 + h * 128;
  const char* vbase = (const char*)VtG + (size_t)(b * 16 + h) * 64 * 2048;

  for (int kt = 0; kt < 8; ++kt) {
    if (kt) __syncthreads();
    // stage K tile [128 keys][64 hd]: 1024 x 16B chunks, src pre-swizzled
#pragma unroll
    for (int p2 = 0; p2 < 4; p2++) {
      int chunk = tid + p2 * 256;                  // 0..1023
      int r = chunk >> 3, cb = (chunk & 7) * 16;   // row, 16B col
      const char* src = kbase + (size_t)(kt * 128 + r) * 2048 + (cb ^ ((r & 7) << 4));
      char* dst = (char*)Kl + (p2 * 256 + wave * 64) * 16;  // wave-uniform
      gld_lds16(src, dst);
    }
    // stage V^T tile [64 hd][128 keys]: 1024 x 16B chunks, src pre-swizzled
#pragma unroll
    for (int p2 = 0; p2 < 4; p2++) {
      int chunk = tid + p2 * 256;
      int d = chunk >> 4, ko = (chunk & 15) * 16;
      const char* src = vbase + (size_t)d * 2048 + kt * 256 + (ko ^ ((d & 7) << 4));
      char* dst = (char*)Vt + (p2 * 256 + wave * 64) * 16;  // wave-uniform
      gld_lds16(src, dst);
    }
    __syncthreads();

#pragma unroll
    for (int g = 0; g < 2; g++) {
      // QK^T: scores for this group's 16 q-rows x 128 keys
      f32x4 st[8];
#pragma unroll
      for (int t8 = 0; t8 < 8; t8++) {
        int krow = t8 * 16 + lr;
        int sw = (krow & 7) << 4;
        const char* kr = (const char*)Kl + krow * 128;
        bf16x8 kb0 = *(const bf16x8*)(kr + ((0 + lk16) ^ sw));
        bf16x8 kb1 = *(const bf16x8*)(kr + ((64 + lk16) ^ sw));
        f32x4 s = {};
        s = mfma16(qa[g][0], kb0, s);
        s = mfma16(qa[g][1], kb1, s);
#pragma unroll
        for (int r = 0; r < 4; r++) {
          float v = s[r] * 0.125f;
          if (CLAMP) v = fminf(fmaxf(v, -100.f), 100.f);
          s[r] = v;
        }
        st[t8] = s;
      }

      // online softmax (rows g4*4+r; keys over 16-lane group + st[8])
#pragma unroll
      for (int r = 0; r < 4; r++) {
        float m01 = fmaxf(st[0][r], st[1][r]), m23 = fmaxf(st[2][r], st[3][r]);
        float m45 = fmaxf(st[4][r], st[5][r]), m67 = fmaxf(st[6][r], st[7][r]);
        float mx = fmaxf(fmaxf(m01, m23), fmaxf(m45, m67));
#pragma unroll
        for (int off = 1; off < 16; off <<= 1) mx = fmaxf(mx, __shfl_xor(mx, off, 64));
        float mnew = fmaxf(mrun[g][r], mx);
        float al = __expf(mrun[g][r] - mnew);
        float sum = 0.f;
#pragma unroll
        for (int t8 = 0; t8 < 8; t8++) {
          float pv = __expf(st[t8][r] - mnew);
          st[t8][r] = pv;
          sum += pv;
        }
#pragma unroll
        for (int off = 1; off < 16; off <<= 1) sum += __shfl_xor(sum, off, 64);
        lsum[g][r] = lsum[g][r] * al + sum;
        mrun[g][r] = mnew;
#pragma unroll
        for (int n = 0; n < 4; n++) acc[g][n][r] *= al;
      }

      // write P (bf16) to per-wave, per-group LDS, swizzled
      char* pb = (char*)&Pl[wave][g][0];
#pragma unroll
      for (int t8 = 0; t8 < 8; t8++) {
        int key = t8 * 16 + lr;
#pragma unroll
        for (int r = 0; r < 4; r++) {
          int prow = g4 * 4 + r;
          *(unsigned short*)(pb + ((prow * 256 + key * 2) ^ ((prow & 7) << 4))) =
              f2bf(st[t8][r]);
        }
      }

      // PV: O += P[16x128] @ V[128x64]  (wave-local; compiler inserts lgkm waits)
      bf16x8 pa[4];
#pragma unroll
      for (int kc = 0; kc < 4; kc++)
        pa[kc] = *(const bf16x8*)(pb + ((lr * 256 + kc * 64 + lk16) ^ ((lr & 7) << 4)));
#pragma unroll
      for (int n = 0; n < 4; n++) {
        int vr = n * 16 + lr;
        int sw = (vr & 7) << 4;
        const char* vp = (const char*)Vt + vr * 256;
#pragma unroll
        for (int kc = 0; kc < 4; kc++) {
          bf16x8 vb = *(const bf16x8*)(vp + ((kc * 64 + lk16) ^ sw));
          acc[g][n] = mfma16(pa[kc], vb, acc[g][n]);
        }
      }
    }
  }

  // epilogue: O / l -> bf16 fused
#pragma unroll
  for (int g = 0; g < 2; g++) {
    const size_t orow0 = (size_t)b * 1024 + qt * 128 + wave * 32 + g * 16 + g4 * 4;
#pragma unroll
    for (int n = 0; n < 4; n++) {
      int col = outColBase + h * 64 + n * 16 + lr;
#pragma unroll
      for (int r = 0; r < 4; r++) {
        float o = acc[g][n][r] / lsum[g][r];
        Out[(orow0 + r) * 2048 + col] = f2bf(o);
      }
    }
  }
}

// ---------------------------------------------------------------------------
// In-place LayerNorm over rows of 1024 fp32 (1 block = 1 row, 256 thr)
// ---------------------------------------------------------------------------
__global__ __launch_bounds__(256) void ln_inplace(float* __restrict__ io,
                                                  const float* __restrict__ gamma,
                                                  const float* __restrict__ beta) {
  __shared__ float red[8];
  int row = blockIdx.x, tid = threadIdx.x;
  float* p = io + (size_t)row * 1024;
  float4 x = ((const float4*)p)[tid];
  float s = x.x + x.y + x.z + x.w;
  float s2 = x.x * x.x + x.y * x.y + x.z * x.z + x.w * x.w;
#pragma unroll
  for (int off = 32; off; off >>= 1) {
    s += __shfl_down(s, off, 64);
    s2 += __shfl_down(s2, off, 64);
  }
  int wv = tid >> 6;
  if ((tid & 63) == 0) { red[wv] = s; red[4 + wv] = s2; }
  __syncthreads();
  if (tid == 0) {
    red[0] = red[0] + red[1] + red[2] + red[3];
    red[4] = red[4] + red[5] + red[6] + red[7];
  }
  __syncthreads();
  float mu = red[0] * (1.f / 1024.f);
  float var = red[4] * (1.f / 1024.f) - mu * mu;
  float inv = rsqrtf(var + 1e-5f);
  float4 g = ((const float4*)gamma)[tid];
  float4 bb = ((const float4*)beta)[tid];
  x.x = (x.x - mu) * inv * g.x + bb.x;
  x.y = (x.y - mu) * inv * g.y + bb.y;
  x.z = (x.z - mu) * inv * g.z + bb.z;
  x.w = (x.w - mu) * inv * g.w + bb.w;
  ((float4*)p)[tid] = x;
}

// ---------------------------------------------------------------------------
extern "C" void kernel_launch(void* const* d_in, const int* in_sizes, int n_in,
                              void* d_out, int out_size, void* d_ws, size_t ws_size,
                              hipStream_t stream) {
  (void)in_sizes; (void)n_in; (void)out_size; (void)ws_size;
  const float* image = (const float*)d_in[0];
  const float* wavef = (const float*)d_in[1];
  const float* Wq_i  = (const float*)d_in[2];
  const float* bq_i  = (const float*)d_in[3];
  const float* Wkv_w = (const float*)d_in[4];
  const float* bkv_w = (const float*)d_in[5];
  const float* Wq_w  = (const float*)d_in[6];
  const float* bq_w  = (const float*)d_in[7];
  const float* Wkv_i = (const float*)d_in[8];
  const float* bkv_i = (const float*)d_in[9];
  const float* Wp    = (const float*)d_in[10];
  const float* bp    = (const float*)d_in[11];
  const float* gamma = (const float*)d_in[12];
  const float* beta  = (const float*)d_in[13];
  float* out = (float*)d_out;

  // workspace layout (80 MiB). fused (16MB) aliases Xi+Xw, safe because
  // attention (writes fused) runs after all projection GEMMs (read Xi/Xw).
  char* ws = (char*)d_ws;
  unsigned short* Xi = (unsigned short*)ws;                       // 8 MiB
  unsigned short* Xw = (unsigned short*)ws + 4096ull * 1024;      // 8 MiB
  unsigned short* fused = (unsigned short*)ws;                    // 16 MiB alias
  size_t off = 16ull << 20;
  auto take = [&](size_t bytes) { void* p = ws + off; off += bytes; return p; };
  unsigned short* Wt_qi  = (unsigned short*)take(2ull << 20);
  unsigned short* Wt_kvw = (unsigned short*)take(4ull << 20);
  unsigned short* Wt_qw  = (unsigned short*)take(2ull << 20);
  unsigned short* Wt_kvi = (unsigned short*)take(4ull << 20);
  unsigned short* Wt_p   = (unsigned short*)take(4ull << 20);
  unsigned short* q_s    = (unsigned short*)take(8ull << 20);
  unsigned short* q_f    = (unsigned short*)take(8ull << 20);
  unsigned short* kvK_w  = (unsigned short*)take(8ull << 20);   // K half, wav
  unsigned short* VtG_w  = (unsigned short*)take(8ull << 20);   // V^T, wav
  unsigned short* kvK_s  = (unsigned short*)take(8ull << 20);   // K half, img
  unsigned short* VtG_s  = (unsigned short*)take(8ull << 20);   // V^T, img

  // 1) convert activations to bf16
  cvt_kernel<<<4096, 256, 0, stream>>>(image, Xi);
  cvt_kernel<<<4096, 256, 0, stream>>>(wavef, Xw);
  // 2) transpose+convert weights to [N][K] bf16
  transpose_cvt<<<dim3(32, 32), 256, 0, stream>>>(Wq_i,  Wt_qi,  1024, 1024);
  transpose_cvt<<<dim3(64, 32), 256, 0, stream>>>(Wkv_w, Wt_kvw, 1024, 2048);
  transpose_cvt<<<dim3(32, 32), 256, 0, stream>>>(Wq_w,  Wt_qw,  1024, 1024);
  transpose_cvt<<<dim3(64, 32), 256, 0, stream>>>(Wkv_i, Wt_kvi, 1024, 2048);
  transpose_cvt<<<dim3(32, 64), 256, 0, stream>>>(Wp,    Wt_p,   2048, 1024);
  // 3) projections (KV GEMMs split: K row-major + V pre-transposed)
  gemm_bt<true><<<dim3(8, 32),  256, 0, stream>>>(Xi, Wt_qi, bq_i, q_s, 4096, 1024, 1024);
  gemm_kv_split<<<dim3(16, 32), 256, 0, stream>>>(Xw, Wt_kvw, bkv_w, kvK_w, VtG_w);
  gemm_bt<true><<<dim3(8, 32),  256, 0, stream>>>(Xw, Wt_qw, bq_w, q_f, 4096, 1024, 1024);
  gemm_kv_split<<<dim3(16, 32), 256, 0, stream>>>(Xi, Wt_kvi, bkv_i, kvK_s, VtG_s);
  // 4) cross attention, QBLK=128 (image->waveform clamps; waveform->image doesn't)
  attn_kernel<true ><<<dim3(8, 64), 256, 0, stream>>>(q_s, kvK_w, VtG_w, fused, 0);
  attn_kernel<false><<<dim3(8, 64), 256, 0, stream>>>(q_f, kvK_s, VtG_s, fused, 1024);
  // 5) output projection (fp32 out) + 6) in-place LayerNorm
  gemm_bt<false><<<dim3(8, 32), 256, 0, stream>>>(fused, Wt_p, bp, out, 4096, 1024, 2048);
  ln_inplace<<<4096, 256, 0, stream>>>(out, gamma, beta);
}